// Round 5
// baseline (720.817 us; speedup 1.0000x reference)
//
#include <hip/hip_runtime.h>

// out[b,y,x] = sum_c sum_{p,q} feat1[b,c,y+p-2,x+q-2] * feat2[b,c,p,q]
// B=4096, C=512, H=W=4.
//
// R2+R4 evidence: two different structures, both with 64B-per-lane loads,
// both pinned at 1.33 TB/s HBM (2.7 TB/s delivered), VALU idle -> the
// 64-lines-per-instruction access pattern is the prime suspect, not MLP.
// This version: fully coalesced loads (lane i -> consecutive float4).
// Ownership: lanes 4k..4k+3 hold rows 0..3 of one channel (A and W).
// 3x shfl_xor gathers give each lane all 4 W rows as wr[t]=row(u^t);
// racc[t][x] += sum_q a[x+q-2]*wr[t][q]  (static indices, 48 FMA/chunk).
// Per-lane remap racc[t] -> out row y=u-(u^t)+2 once per b, then the
// verified butterfly reduction. 2 waves per b, no inner barriers.

__device__ __forceinline__ float4 shflx4(float4 v, int m) {
    float4 r;
    r.x = __shfl_xor(v.x, m, 64);
    r.y = __shfl_xor(v.y, m, 64);
    r.z = __shfl_xor(v.z, m, 64);
    r.w = __shfl_xor(v.w, m, 64);
    return r;
}

__global__ __launch_bounds__(256, 6) void corr_kernel(
        const float4* __restrict__ feat1,
        const float4* __restrict__ feat2,
        float* __restrict__ out) {
    const int tid  = threadIdx.x;
    const int lane = tid & 63;
    const int wv   = tid >> 6;                 // 0..3
    const int bsub = wv >> 1;                  // which of this block's 2 b's
    const int half = wv & 1;                   // which half of the channels
    const int b    = blockIdx.x * 2 + bsub;
    const int u    = lane & 3;                 // row (h) this lane owns

    // float4-unit base: b*2048 + half*1024 + lane  (perfectly coalesced)
    const size_t kbase = (size_t)b * 2048 + (size_t)half * 1024 + lane;

    float racc[4][4];
    #pragma unroll
    for (int t = 0; t < 4; ++t)
        #pragma unroll
        for (int x = 0; x < 4; ++x) racc[t][x] = 0.f;

    float4 Abuf[2], Wbuf[2];
    Abuf[0] = feat1[kbase];
    Wbuf[0] = feat2[kbase];

    #pragma unroll
    for (int j = 0; j < 16; ++j) {             // 16 chunks x 64 float4
        const int cur = j & 1, nxt = cur ^ 1;  // static after unroll
        if (j < 15) {                          // prefetch next chunk
            Abuf[nxt] = feat1[kbase + (size_t)(j + 1) * 64];
            Wbuf[nxt] = feat2[kbase + (size_t)(j + 1) * 64];
        }
        // keep the prefetch above the compute (R2 failure: scheduler sank
        // loads to minimize VGPRs and serialized the stream)
        __builtin_amdgcn_sched_barrier(0);

        const float4 Av = Abuf[cur];
        const float4 w0 = Wbuf[cur];
        const float4 w1 = shflx4(w0, 1);       // row u^1 (same channel: xor
        const float4 w2 = shflx4(w0, 2);       //  of bits 0-1 stays in group)
        const float4 w3 = shflx4(w0, 3);       // row u^3

        const float a[4] = {Av.x, Av.y, Av.z, Av.w};
        const float wr[4][4] = {
            {w0.x, w0.y, w0.z, w0.w},
            {w1.x, w1.y, w1.z, w1.w},
            {w2.x, w2.y, w2.z, w2.w},
            {w3.x, w3.y, w3.z, w3.w}};

        #pragma unroll
        for (int t = 0; t < 4; ++t)
            #pragma unroll
            for (int x = 0; x < 4; ++x)
                #pragma unroll
                for (int kk = 0; kk < 4; ++kk) {
                    const int v = x + kk - 2;  // feat1 column
                    if (v < 0 || v > 3) continue;
                    racc[t][x] = fmaf(a[v], wr[t][kk], racc[t][x]);
                }
    }

    // Per-lane remap: racc[t] is the row-correlation of a-row u with w-row
    // p=u^t; it belongs to out-row y = u-p+2. Enumerated per u (12 valid
    // (u,p) pairs), resolved with compile-time-unrolled selects:
    //   y=2: t=0 for all u.  y=1: u0,u2 <- t1; u1 <- t3.
    //   y=3: u1,u3 <- t1; u2 <- t3.  y=0: u0,u1 <- t2.
    float v16[16];
    #pragma unroll
    for (int x = 0; x < 4; ++x) {
        v16[2 * 4 + x] = racc[0][x];
        v16[1 * 4 + x] = (u == 0 || u == 2) ? racc[1][x]
                        : (u == 1 ? racc[3][x] : 0.f);
        v16[3 * 4 + x] = (u == 1 || u == 3) ? racc[1][x]
                        : (u == 2 ? racc[3][x] : 0.f);
        v16[0 * 4 + x] = (u < 2) ? racc[2][x] : 0.f;
    }

    // Value-splitting butterfly (verified R2/R4): after 4 steps lane l holds
    // component (l&15) summed over its 16-lane group; 2 xor steps finish.
    #pragma unroll
    for (int k = 0; k < 4; ++k) {
        const int m = 1 << k;
        const int pairs = 8 >> k;
        const bool sel = (lane >> k) & 1;
        float wtmp[8];
        #pragma unroll
        for (int p = 0; p < pairs; ++p) {
            float keep = sel ? v16[2 * p + 1] : v16[2 * p];
            float send = sel ? v16[2 * p]     : v16[2 * p + 1];
            float recv = __shfl_xor(send, m, 64);
            wtmp[p] = keep + recv;
        }
        #pragma unroll
        for (int p = 0; p < pairs; ++p) v16[p] = wtmp[p];
    }
    float r = v16[0];
    r += __shfl_xor(r, 16, 64);
    r += __shfl_xor(r, 32, 64);
    // lane l holds component (l&15) of this wave's half-channel partial sum

    __shared__ float red[4][16];
    if (lane < 16) red[wv][lane] = r;
    __syncthreads();
    if (tid < 32) {                            // combine halves, store 2 b's
        const int bs   = tid >> 4;             // 0/1 -> block's b
        const int comp = tid & 15;
        const float s = red[bs * 2 + 0][comp] + red[bs * 2 + 1][comp];
        out[(size_t)(blockIdx.x * 2 + bs) * 16 + comp] = s;
    }
}

extern "C" void kernel_launch(void* const* d_in, const int* in_sizes, int n_in,
                              void* d_out, int out_size, void* d_ws, size_t ws_size,
                              hipStream_t stream) {
    const float4* feat1 = (const float4*)d_in[0];
    const float4* feat2 = (const float4*)d_in[1];
    float* out = (float*)d_out;
    const int B = in_sizes[0] / (512 * 16);    // 4096
    corr_kernel<<<dim3(B / 2), dim3(256), 0, stream>>>(feat1, feat2, out);
}

// Round 6
// 507.166 us; speedup vs baseline: 1.4213x; 1.4213x over previous
//
#include <hip/hip_runtime.h>

// out[b,y,x] = sum_c sum_{p,q} feat1[b,c,y+p-2,x+q-2] * feat2[b,c,p,q]
// B=4096, C=512, H=W=4.
//
// R5 post-mortem: coalesced layout doubled actual HBM rate (2.7 TB/s) but the
// Abuf[cur]/Wbuf[cur] double-buffer went to SCRATCH (j-loop didn't fully
// unroll -> runtime index; WRITE_SIZE 659 MB, 1.25 KB/thread = 16 chunks x
// 4 float4). Fix: named double-buffer vars A0/W0/A1/W1, j += 2 — runtime
// indexing structurally impossible. launch_bounds back to (256,4) (R4: no
// spill at VGPR 56).

__device__ __forceinline__ float4 shflx4(float4 v, int m) {
    float4 r;
    r.x = __shfl_xor(v.x, m, 64);
    r.y = __shfl_xor(v.y, m, 64);
    r.z = __shfl_xor(v.z, m, 64);
    r.w = __shfl_xor(v.w, m, 64);
    return r;
}

__global__ __launch_bounds__(256, 4) void corr_kernel(
        const float4* __restrict__ feat1,
        const float4* __restrict__ feat2,
        float* __restrict__ out) {
    const int tid  = threadIdx.x;
    const int lane = tid & 63;
    const int wv   = tid >> 6;                 // 0..3
    const int b    = blockIdx.x * 2 + (wv >> 1);
    const int half = wv & 1;                   // which half of the channels
    const int u    = lane & 3;                 // row (h) this lane owns

    // float4-unit base: lane i -> consecutive float4 (perfectly coalesced)
    const size_t kbase = (size_t)b * 2048 + (size_t)half * 1024 + lane;

    float racc[4][4];
    #pragma unroll
    for (int t = 0; t < 4; ++t)
        #pragma unroll
        for (int x = 0; x < 4; ++x) racc[t][x] = 0.f;

    // racc[t] += rowcorr(a-row u, w-row u^t); all indices compile-time.
    auto body = [&](float4 Av, float4 Wv) {
        const float4 w1v = shflx4(Wv, 1);      // row u^1 (xor of bits 0-1
        const float4 w2v = shflx4(Wv, 2);      //  stays inside the 4-lane
        const float4 w3v = shflx4(Wv, 3);      //  channel group)
        const float a[4] = {Av.x, Av.y, Av.z, Av.w};
        const float wr[4][4] = {
            {Wv.x,  Wv.y,  Wv.z,  Wv.w},
            {w1v.x, w1v.y, w1v.z, w1v.w},
            {w2v.x, w2v.y, w2v.z, w2v.w},
            {w3v.x, w3v.y, w3v.z, w3v.w}};
        #pragma unroll
        for (int t = 0; t < 4; ++t)
            #pragma unroll
            for (int x = 0; x < 4; ++x)
                #pragma unroll
                for (int kk = 0; kk < 4; ++kk) {
                    const int vv = x + kk - 2; // feat1 column
                    if (vv < 0 || vv > 3) continue;
                    racc[t][x] = fmaf(a[vv], wr[t][kk], racc[t][x]);
                }
    };

    float4 A0 = feat1[kbase];
    float4 W0 = feat2[kbase];
    float4 A1, W1;

    #pragma unroll
    for (int j = 0; j < 16; j += 2) {          // 16 chunks x 64 float4
        A1 = feat1[kbase + (size_t)(j + 1) * 64];
        W1 = feat2[kbase + (size_t)(j + 1) * 64];
        __builtin_amdgcn_sched_barrier(0);     // keep prefetch above compute
        body(A0, W0);
        if (j + 2 < 16) {
            A0 = feat1[kbase + (size_t)(j + 2) * 64];
            W0 = feat2[kbase + (size_t)(j + 2) * 64];
        }
        __builtin_amdgcn_sched_barrier(0);
        body(A1, W1);
    }

    // Per-lane remap: racc[t] = rowcorr(a_u, w_p) with p=u^t belongs to
    // out-row y = u-p+2. Enumerated per u (12 valid (u,p) pairs):
    //   y=2: t=0 all u.  y=1: u0,u2 <- t1; u1 <- t3.
    //   y=3: u1,u3 <- t1; u2 <- t3.  y=0: u0,u1 <- t2.
    float v16[16];
    #pragma unroll
    for (int x = 0; x < 4; ++x) {
        v16[2 * 4 + x] = racc[0][x];
        v16[1 * 4 + x] = (u == 0 || u == 2) ? racc[1][x]
                        : (u == 1 ? racc[3][x] : 0.f);
        v16[3 * 4 + x] = (u == 1 || u == 3) ? racc[1][x]
                        : (u == 2 ? racc[3][x] : 0.f);
        v16[0 * 4 + x] = (u < 2) ? racc[2][x] : 0.f;
    }

    // Value-splitting butterfly (verified R2/R4/R5): after 4 steps lane l
    // holds component (l&15) summed over its 16-lane group; 2 xor steps
    // finish the wave.
    #pragma unroll
    for (int k = 0; k < 4; ++k) {
        const int m = 1 << k;
        const int pairs = 8 >> k;
        const bool sel = (lane >> k) & 1;
        float wtmp[8];
        #pragma unroll
        for (int p = 0; p < pairs; ++p) {
            float keep = sel ? v16[2 * p + 1] : v16[2 * p];
            float send = sel ? v16[2 * p]     : v16[2 * p + 1];
            float recv = __shfl_xor(send, m, 64);
            wtmp[p] = keep + recv;
        }
        #pragma unroll
        for (int p = 0; p < pairs; ++p) v16[p] = wtmp[p];
    }
    float r = v16[0];
    r += __shfl_xor(r, 16, 64);
    r += __shfl_xor(r, 32, 64);
    // lane l holds component (l&15) of this wave's half-channel partial sum

    __shared__ float red[4][16];
    if (lane < 16) red[wv][lane] = r;
    __syncthreads();
    if (tid < 32) {                            // combine halves, store 2 b's
        const int bs   = tid >> 4;
        const int comp = tid & 15;
        const float s = red[bs * 2 + 0][comp] + red[bs * 2 + 1][comp];
        out[(size_t)(blockIdx.x * 2 + bs) * 16 + comp] = s;
    }
}

extern "C" void kernel_launch(void* const* d_in, const int* in_sizes, int n_in,
                              void* d_out, int out_size, void* d_ws, size_t ws_size,
                              hipStream_t stream) {
    const float4* feat1 = (const float4*)d_in[0];
    const float4* feat2 = (const float4*)d_in[1];
    float* out = (float*)d_out;
    const int B = in_sizes[0] / (512 * 16);    // 4096
    corr_kernel<<<dim3(B / 2), dim3(256), 0, stream>>>(feat1, feat2, out);
}